// Round 2
// baseline (705.529 us; speedup 1.0000x reference)
//
#include <hip/hip_runtime.h>

#define NGROUPS 32
#define BATCH   8
#define CHANNELS 64
#define GN_EPS 1e-5f

// ws layout (floats): s1[BATCH*NGROUPS] | s2[BATCH*NGROUPS] | cnt[BATCH]
// cnt[b] holds the POINT count Nb (not float4 count).
#define WS_S2   (BATCH * NGROUPS)
#define WS_CNT  (2 * BATCH * NGROUPS)
#define WS_TOT  (2 * BATCH * NGROUPS + BATCH)

typedef float f32x4 __attribute__((ext_vector_type(4)));

__global__ void zero_ws_kernel(float* __restrict__ ws) {
    for (int i = threadIdx.x; i < WS_TOT; i += blockDim.x) ws[i] = 0.0f;
}

// Per float4 (4 channels = quad q): groups 2q (v.x,v.y) and 2q+1 (v.z,v.w)
// are ENTIRELY inside this float4 for this point. So each lane's pair-sums
// are complete per-point group sums -> accumulate straight into an LDS
// [BATCH][NGROUPS] table with ds_add_f32, no per-batch register replication.
__global__ __launch_bounds__(256) void stats_kernel(
    const float4* __restrict__ f4, const int* __restrict__ bidx,
    float* __restrict__ ws, int n_f4)
{
    __shared__ float l_s1[BATCH * NGROUPS];
    __shared__ float l_s2[BATCH * NGROUPS];
    __shared__ float l_cnt[BATCH];
    for (int i = threadIdx.x; i < BATCH * NGROUPS; i += blockDim.x) {
        l_s1[i] = 0.0f; l_s2[i] = 0.0f;
    }
    if (threadIdx.x < BATCH) l_cnt[threadIdx.x] = 0.0f;
    __syncthreads();

    const int stride = gridDim.x * blockDim.x;
    const int j0 = blockIdx.x * blockDim.x + threadIdx.x;
    const int q = j0 & 15;          // loop-invariant quad index (stride%16==0)
    const int g0 = 2 * q;           // first group covered by this quad

    int j = j0;
    for (; j + stride < n_f4; j += 2 * stride) {
        float4 v0 = f4[j];
        float4 v1 = f4[j + stride];
        int b0 = bidx[j >> 4];
        int b1 = bidx[(j + stride) >> 4];

        float p00 = v0.x + v0.y, p01 = v0.z + v0.w;
        float q00 = fmaf(v0.x, v0.x, v0.y * v0.y);
        float q01 = fmaf(v0.z, v0.z, v0.w * v0.w);
        float p10 = v1.x + v1.y, p11 = v1.z + v1.w;
        float q10 = fmaf(v1.x, v1.x, v1.y * v1.y);
        float q11 = fmaf(v1.z, v1.z, v1.w * v1.w);

        // XOR-by-batch swizzle: without it bank = 2q for all 4 same-q lanes
        // of a wave (guaranteed 4-way conflict); with it, distinct b ->
        // distinct bank. Bit0 untouched (2b even) so g0/g0+1 stay adjacent.
        int a0 = b0 * NGROUPS + (g0 ^ (2 * b0));
        int a1 = b1 * NGROUPS + (g0 ^ (2 * b1));
        atomicAdd(&l_s1[a0],     p00);
        atomicAdd(&l_s1[a0 + 1], p01);
        atomicAdd(&l_s2[a0],     q00);
        atomicAdd(&l_s2[a0 + 1], q01);
        atomicAdd(&l_s1[a1],     p10);
        atomicAdd(&l_s1[a1 + 1], p11);
        atomicAdd(&l_s2[a1],     q10);
        atomicAdd(&l_s2[a1 + 1], q11);
        if (q == 0) {   // one lane per point counts it
            atomicAdd(&l_cnt[b0], 1.0f);
            atomicAdd(&l_cnt[b1], 1.0f);
        }
    }
    if (j < n_f4) {
        float4 v0 = f4[j];
        int b0 = bidx[j >> 4];
        float p00 = v0.x + v0.y, p01 = v0.z + v0.w;
        float q00 = fmaf(v0.x, v0.x, v0.y * v0.y);
        float q01 = fmaf(v0.z, v0.z, v0.w * v0.w);
        int a0 = b0 * NGROUPS + (g0 ^ (2 * b0));
        atomicAdd(&l_s1[a0],     p00);
        atomicAdd(&l_s1[a0 + 1], p01);
        atomicAdd(&l_s2[a0],     q00);
        atomicAdd(&l_s2[a0 + 1], q01);
        if (q == 0) atomicAdd(&l_cnt[b0], 1.0f);
    }
    __syncthreads();

    // Flush: un-swizzle (g = gx ^ 2b, involution) and push to global.
    for (int i = threadIdx.x; i < BATCH * NGROUPS; i += blockDim.x) {
        int b = i >> 5, gx = i & (NGROUPS - 1);
        int g = gx ^ (2 * b);
        atomicAdd(&ws[b * NGROUPS + g], l_s1[i]);
        atomicAdd(&ws[WS_S2 + b * NGROUPS + g], l_s2[i]);
    }
    if (threadIdx.x < BATCH) atomicAdd(&ws[WS_CNT + threadIdx.x], l_cnt[threadIdx.x]);
}

#define LDS_STRIDE 68   // 64 + 4: keeps 16B alignment for [b][4q], breaks bank pattern

__global__ __launch_bounds__(256) void norm_kernel(
    const float4* __restrict__ f4, const int* __restrict__ bidx,
    const float* __restrict__ weight, const float* __restrict__ bias,
    const float* __restrict__ ws, float4* __restrict__ out4, int n_f4)
{
    __shared__ __align__(16) float sc[BATCH][LDS_STRIDE];
    __shared__ __align__(16) float sh[BATCH][LDS_STRIDE];

    for (int t = threadIdx.x; t < BATCH * CHANNELS; t += blockDim.x) {
        int b = t >> 6, c = t & 63, g = c >> 1;
        float s1v = ws[b * NGROUPS + g];
        float s2v = ws[WS_S2 + b * NGROUPS + g];
        float cntf = ws[WS_CNT + b];              // = Nb (points in batch b)
        float denom = fmaxf(cntf * 2.0f, 1.0f);   // Nb * Cg
        float mean = s1v / denom;
        float var = s2v / denom - mean * mean;
        float inv = rsqrtf(var + GN_EPS);
        float w = weight[c];
        sc[b][c] = inv * w;
        sh[b][c] = bias[c] - mean * inv * w;
    }
    __syncthreads();

    const int stride = gridDim.x * blockDim.x;
    const int j0 = blockIdx.x * blockDim.x + threadIdx.x;
    const int q4 = (j0 & 15) * 4;   // loop-invariant channel base

    int j = j0;
    for (; j + stride < n_f4; j += 2 * stride) {
        float4 v0 = f4[j];
        float4 v1 = f4[j + stride];
        int b0 = bidx[j >> 4];
        int b1 = bidx[(j + stride) >> 4];
        float4 s0 = *(const float4*)&sc[b0][q4];
        float4 h0 = *(const float4*)&sh[b0][q4];
        float4 s1v = *(const float4*)&sc[b1][q4];
        float4 h1 = *(const float4*)&sh[b1][q4];
        f32x4 o0, o1;
        o0.x = fmaf(v0.x, s0.x, h0.x);
        o0.y = fmaf(v0.y, s0.y, h0.y);
        o0.z = fmaf(v0.z, s0.z, h0.z);
        o0.w = fmaf(v0.w, s0.w, h0.w);
        o1.x = fmaf(v1.x, s1v.x, h1.x);
        o1.y = fmaf(v1.y, s1v.y, h1.y);
        o1.z = fmaf(v1.z, s1v.z, h1.z);
        o1.w = fmaf(v1.w, s1v.w, h1.w);
        // Non-temporal: the 256 MB out stream must not evict `features`
        // (exactly L3-sized) from Infinity Cache between kernels/iterations.
        __builtin_nontemporal_store(o0, (f32x4*)(out4 + j));
        __builtin_nontemporal_store(o1, (f32x4*)(out4 + j + stride));
    }
    if (j < n_f4) {
        float4 v0 = f4[j];
        int b0 = bidx[j >> 4];
        float4 s0 = *(const float4*)&sc[b0][q4];
        float4 h0 = *(const float4*)&sh[b0][q4];
        f32x4 o0;
        o0.x = fmaf(v0.x, s0.x, h0.x);
        o0.y = fmaf(v0.y, s0.y, h0.y);
        o0.z = fmaf(v0.z, s0.z, h0.z);
        o0.w = fmaf(v0.w, s0.w, h0.w);
        __builtin_nontemporal_store(o0, (f32x4*)(out4 + j));
    }
}

extern "C" void kernel_launch(void* const* d_in, const int* in_sizes, int n_in,
                              void* d_out, int out_size, void* d_ws, size_t ws_size,
                              hipStream_t stream) {
    const float* features = (const float*)d_in[0];
    const float* weight   = (const float*)d_in[1];
    const float* bias     = (const float*)d_in[2];
    const int*   bidx     = (const int*)d_in[3];
    float* ws = (float*)d_ws;
    float* out = (float*)d_out;

    const int n_f4 = in_sizes[0] / 4;   // N*C/4 float4s

    zero_ws_kernel<<<1, 256, 0, stream>>>(ws);
    stats_kernel<<<2048, 256, 0, stream>>>((const float4*)features, bidx, ws, n_f4);
    norm_kernel<<<2048, 256, 0, stream>>>((const float4*)features, bidx, weight, bias,
                                          ws, (float4*)out, n_f4);
}